// Round 25
// baseline (208.490 us; speedup 1.0000x reference)
//
#include <hip/hip_runtime.h>
#include <hip/hip_bf16.h>
#include <hip/hip_cooperative_groups.h>

namespace cg = cooperative_groups;

// NonLocalBlock fp32 -> reduced bf16 MFMA, MI355X.
// r25: SINGLE COOPERATIVE MEGA-KERNEL. r24's 8x-attn diagnostic measured
// attn_true = 17.9us -> baseline 47.6 = attn 18 + convs ~7 + ~23us of launch
// gaps/dispatch overhead. This round removes the overhead: one cooperative
// launch (256 blocks x 512), phases A(conv3)/B(attn,r22-verbatim)/C(conv_out)
// separated by __threadfence + grid.sync (G16 cross-XCD visibility).
// Math identical to r22 (validated): absmax 7.63e-6.
#define BATCH 2
#define CIN   64
#define COUT  32
#define HW    6400
#define PB    (COUT*HW)      // 204800 elems per batch (M-view 6400x32)
#define XB    (CIN*HW)
#define LOG2E 1.4426950408889634f

typedef __attribute__((ext_vector_type(8))) short  bf16x8;
typedef __attribute__((ext_vector_type(4))) float  f32x4;

typedef unsigned short ushort;
typedef unsigned int   uint;

__device__ inline uint pk2(float a, float b) {   // RNE pack (conv phase only)
  __hip_bfloat162 h = __float22bfloat162_rn(make_float2(a, b));
  union { __hip_bfloat162 h2; uint u; } cv; cv.h2 = h;
  return cv.u;
}
// truncation pack: lo short = bf16_trunc(a), hi short = bf16_trunc(b)
__device__ inline uint pkt(float a, float b) {
  return (__float_as_uint(b) & 0xFFFF0000u) | (__float_as_uint(a) >> 16);
}

#define MFMA16(a, bop, c) __builtin_amdgcn_mfma_f32_16x16x32_bf16((a), (bop), (c), 0, 0, 0)

// ---------------------------------------------------------------------------
// Mega-kernel: 256 blocks x 512 threads, cooperative.
// Phase A (conv3, r22 math): 600 units of 128 threads; unit u =
//   ((b*3 + which)*2 + oh)*50 + chunk; block has 4 quarter-units.
//   theta (0): *LOG2E -> T_hi.  phi (1): -> P_hi.
//   g (2): packed linear-fragment GtT: value (o,s) is G_M[m][c],
//     m = o*200+(s>>5), c = s&31; pk = inv_sigma(m&31);
//     idx = (m>>5)*1024 + (c>>4)*512 + ((pk>>3)*16 + (c&15))*8 + (pk&7)
// Phase B (attn, r22 verbatim): blocks 0..199; b = blk/100, q_blk = blk%100.
// Phase C (conv_out): 200 units of 128 threads; u = blk*4+quarter < 200.
// ---------------------------------------------------------------------------
__global__ __launch_bounds__(512) void mega_kernel(
    const float* __restrict__ x,
    const float* __restrict__ w_t, const float* __restrict__ b_t,
    const float* __restrict__ w_p, const float* __restrict__ b_p,
    const float* __restrict__ w_g, const float* __restrict__ b_g,
    const float* __restrict__ wy,  const float* __restrict__ by,
    ushort* __restrict__ T_hi, ushort* __restrict__ P_hi,
    ushort* __restrict__ GtT,  float* __restrict__ Yb,
    float* __restrict__ z) {
  cg::grid_group grid = cg::this_grid();
  const int tid = threadIdx.x;

  __shared__ __align__(16) char smraw[17408];    // shared phase arena

  // ======================= Phase A: three 1x1 convs =======================
  {
    float* wsm = (float*)smraw;                  // [4][1024]
    const int quarter = tid >> 7;
    const int t128    = tid & 127;
    const int u       = blockIdx.x * 4 + quarter;   // 0..1023
    const bool active = (u < 600);
    int bb = 0, which = 0, oh = 0, chunk = 0;
    if (active) {
      bb = u / 300; const int r = u % 300;
      which = r / 100; const int r2 = r % 100;
      oh = r2 / 50; chunk = r2 % 50;
    }
    const float* w  = (which == 0) ? w_t : (which == 1) ? w_p : w_g;
    const float* bv = (which == 0) ? b_t : (which == 1) ? b_p : b_g;
    if (active) {
      for (int i = t128; i < 16 * CIN; i += 128)
        wsm[quarter * 1024 + i] = w[oh * 16 * CIN + i];
    }
    __syncthreads();
    if (active) {
      const int s = chunk * 128 + t128;
      float xr[CIN];
#pragma unroll
      for (int c = 0; c < CIN; ++c) xr[c] = x[bb * XB + c * HW + s];

      for (int oi = 0; oi < 16; ++oi) {
        const int o = oh * 16 + oi;
        const float4* wr = (const float4*)&wsm[quarter * 1024 + oi * CIN];
        float acc = 0.f;
#pragma unroll
        for (int q = 0; q < CIN / 4; ++q) {
          float4 wv = wr[q];
          acc += wv.x*xr[4*q] + wv.y*xr[4*q+1] + wv.z*xr[4*q+2] + wv.w*xr[4*q+3];
        }
        acc += bv[o];
        if (which == 0) acc *= LOG2E;            // exp(S) == exp2(S*log2e)
        const ushort hb = (ushort)(pk2(acc, 0.f) & 0xFFFFu);
        if (which == 2) {
          const int m  = o * 200 + (s >> 5);
          const int mm = m & 31;
          const int pk = 16*((mm>>3)&1) + 8*((mm>>2)&1) + 4*((mm>>4)&1) + (mm&3);
          const int ln = (pk >> 3) * 16 + (s & 15);
          const int idx = ((m >> 5) << 10) + (((s >> 4) & 1) << 9)
                        + (ln << 3) + (pk & 7);
          GtT[bb * PB + idx] = hb;
        } else {
          const int f = bb * PB + o * HW + s;
          if (which == 0) T_hi[f] = hb; else P_hi[f] = hb;
        }
      }
    }
  }
  __threadfence();
  grid.sync();

  // ======================= Phase B: fused attention =======================
  if (blockIdx.x < 200) {
    const int b     = blockIdx.x / 100;
    const int q_blk = blockIdx.x % 100;          // 64 queries each
    const int w     = tid >> 6;                  // wave 0..7 = key slice
    const int lane  = tid & 63;
    const int l15   = lane & 15;
    const int g     = lane >> 4;

    float* yl = (float*)smraw;                   // [8*16][33] + dl
    float* dl = yl + 8 * 16 * 33;

    const int kbase = w * 32;

    bf16x8 t_hi[4];
#pragma unroll
    for (int s2 = 0; s2 < 4; ++s2) {
      const int qrow = q_blk * 64 + s2 * 16 + l15;
      t_hi[s2] = *(const bf16x8*)&T_hi[b * PB + qrow * 32 + g * 8];
    }
    asm volatile("s_waitcnt vmcnt(0)" ::: "memory");
    __builtin_amdgcn_sched_barrier(0);

    union { uint u[4]; bf16x8 v; } g2u;
    {
      const uint ov = (l15 == 0) ? 0x3F803F80u : 0u;
      g2u.u[0] = ov; g2u.u[1] = ov; g2u.u[2] = ov; g2u.u[3] = ov;
    }
    const bf16x8 g2 = g2u.v;

    const ushort* pg = P_hi + b * PB + (kbase + l15) * 32 + g * 8;
    const ushort* gg = GtT + b * PB + (w << 10) + lane * 8;

    f32x4 acc0[4] = {{0,0,0,0},{0,0,0,0},{0,0,0,0},{0,0,0,0}};
    f32x4 acc1[4] = {{0,0,0,0},{0,0,0,0},{0,0,0,0},{0,0,0,0}};
    f32x4 acc2[4] = {{0,0,0,0},{0,0,0,0},{0,0,0,0},{0,0,0,0}};

    bf16x8 paA, pbA, g0A, g1A;
    bf16x8 paB, pbB, g0B, g1B;
    bf16x8 paC, pbC, g0C, g1C;

#define ISSUE(SUF, t) do {                                                   \
    const ushort* _pp = pg + (size_t)(t) * 8192;                             \
    const ushort* _gp = gg + (size_t)(t) * 8192;                             \
    asm volatile("global_load_dwordx4 %0, %1, off"                           \
                 : "=&v"(pa##SUF) : "v"(_pp));                               \
    asm volatile("global_load_dwordx4 %0, %1, off"                           \
                 : "=&v"(pb##SUF) : "v"(_pp + 512));                         \
    asm volatile("global_load_dwordx4 %0, %1, off"                           \
                 : "=&v"(g0##SUF) : "v"(_gp));                               \
    asm volatile("global_load_dwordx4 %0, %1, off"                           \
                 : "=&v"(g1##SUF) : "v"(_gp + 512));                         \
  } while (0)

#define WAITVM(n) do {                                                       \
    asm volatile("s_waitcnt vmcnt(" #n ")" ::: "memory");                    \
    __builtin_amdgcn_sched_barrier(0);                                       \
  } while (0)

#define COMPUTE(SUF)                                                         \
  _Pragma("unroll")                                                          \
  for (int s2 = 0; s2 < 4; ++s2) {                                           \
    f32x4 sa = {0.f, 0.f, 0.f, 0.f};                                         \
    f32x4 sb = {0.f, 0.f, 0.f, 0.f};                                         \
    sa = MFMA16(pa##SUF, t_hi[s2], sa);                                      \
    sb = MFMA16(pb##SUF, t_hi[s2], sb);                                      \
    const float ea0 = __builtin_amdgcn_exp2f(sa[0]);                         \
    const float ea1 = __builtin_amdgcn_exp2f(sa[1]);                         \
    const float ea2 = __builtin_amdgcn_exp2f(sa[2]);                         \
    const float ea3 = __builtin_amdgcn_exp2f(sa[3]);                         \
    const float eb0 = __builtin_amdgcn_exp2f(sb[0]);                         \
    const float eb1 = __builtin_amdgcn_exp2f(sb[1]);                         \
    const float eb2 = __builtin_amdgcn_exp2f(sb[2]);                         \
    const float eb3 = __builtin_amdgcn_exp2f(sb[3]);                         \
    union { uint u[4]; bf16x8 v; } ph;                                       \
    ph.u[0] = pkt(ea0, ea1); ph.u[1] = pkt(ea2, ea3);                        \
    ph.u[2] = pkt(eb0, eb1); ph.u[3] = pkt(eb2, eb3);                        \
    acc0[s2] = MFMA16(ph.v, g0##SUF, acc0[s2]);                              \
    acc1[s2] = MFMA16(ph.v, g1##SUF, acc1[s2]);                              \
    acc2[s2] = MFMA16(ph.v, g2, acc2[s2]);                                   \
  }

    ISSUE(A, 0);
    ISSUE(B, 1);
    ISSUE(C, 2);

    for (int i = 0; i < 21; i += 3) {
      WAITVM(8); COMPUTE(A); ISSUE(A, i + 3);
      WAITVM(8); COMPUTE(B); ISSUE(B, i + 4);
      WAITVM(8); COMPUTE(C); ISSUE(C, i + 5);
    }
    WAITVM(8); COMPUTE(A); ISSUE(A, 24);
    WAITVM(8); COMPUTE(B);
    WAITVM(4); COMPUTE(C);
    WAITVM(0); COMPUTE(A);

#undef ISSUE
#undef WAITVM
#undef COMPUTE

    const int c   = tid & 31;
    const int row = (tid >> 5) & 15;

#pragma unroll
    for (int p = 0; p < 4; ++p) {
      __syncthreads();
      {
        const int s2 = p;
#pragma unroll
        for (int r = 0; r < 4; ++r) {
          yl[(w * 16 + 4 * g + r) * 33 + l15]      = acc0[s2][r];
          yl[(w * 16 + 4 * g + r) * 33 + 16 + l15] = acc1[s2][r];
        }
        if (l15 == 0) {
#pragma unroll
          for (int r = 0; r < 4; ++r)
            dl[w * 16 + 4 * g + r] = acc2[s2][r];
        }
      }
      __syncthreads();

      float y = 0.f, d = 0.f;
#pragma unroll
      for (int k2 = 0; k2 < 8; ++k2) {
        y += yl[(k2 * 16 + row) * 33 + c];
        d += dl[k2 * 16 + row];
      }
      const int qrow = q_blk * 64 + p * 16 + row;
      Yb[(size_t)b * PB + qrow * 32 + c] = y / d;
    }
  }
  __threadfence();
  grid.sync();

  // ======================= Phase C: final 1x1 conv ========================
  {
    float* wsm = (float*)smraw;                  // [4][1024]
    const int quarter = tid >> 7;
    const int t128    = tid & 127;
    const int u       = blockIdx.x * 4 + quarter;
    const bool active = (u < 200);
    int bb = 0, ih = 0, chunk = 0;
    if (active) {
      bb = u / 100; const int r = u % 100;
      ih = r / 50; chunk = r % 50;
    }
    if (active) {
      for (int i = t128; i < 32 * COUT; i += 128)
        wsm[quarter * 1024 + i] = wy[ih * 32 * COUT + i];
    }
    __syncthreads();
    if (active) {
      const int s = chunk * 128 + t128;
      float yr[COUT];
#pragma unroll
      for (int o = 0; o < COUT; ++o)
        yr[o] = Yb[(size_t)bb * PB + o * HW + s];

      for (int ii = 0; ii < 32; ++ii) {
        const int i = ih * 32 + ii;
        const float4* wr = (const float4*)&wsm[quarter * 1024 + ii * COUT];
        float acc = 0.f;
#pragma unroll
        for (int q = 0; q < COUT / 4; ++q) {
          float4 wv = wr[q];
          acc += wv.x*yr[4*q] + wv.y*yr[4*q+1] + wv.z*yr[4*q+2] + wv.w*yr[4*q+3];
        }
        z[(size_t)bb * XB + i * HW + s] = acc + by[i];
      }
    }
  }
}

// ---------------------------------------------------------------------------
extern "C" void kernel_launch(void* const* d_in, const int* in_sizes, int n_in,
                              void* d_out, int out_size, void* d_ws, size_t ws_size,
                              hipStream_t stream) {
  const float* x       = (const float*)d_in[0];
  const float* w_g     = (const float*)d_in[1];
  const float* b_g     = (const float*)d_in[2];
  const float* w_phi   = (const float*)d_in[3];
  const float* b_phi   = (const float*)d_in[4];
  const float* w_theta = (const float*)d_in[5];
  const float* b_theta = (const float*)d_in[6];
  const float* w_y     = (const float*)d_in[7];
  const float* b_y     = (const float*)d_in[8];
  float* z = (float*)d_out;

  char* base = (char*)d_ws;
  const size_t BF = (size_t)BATCH * PB * sizeof(ushort);  // 819200 B
  ushort* T_hi = (ushort*)(base);
  ushort* P_hi = (ushort*)(base + 1 * BF);
  ushort* GtT  = (ushort*)(base + 2 * BF);
  float*  Y    = (float*)(base + 3 * BF);                  // B*PB f32 final y

  void* kargs[] = {
    (void*)&x,
    (void*)&w_theta, (void*)&b_theta,
    (void*)&w_phi,   (void*)&b_phi,
    (void*)&w_g,     (void*)&b_g,
    (void*)&w_y,     (void*)&b_y,
    (void*)&T_hi, (void*)&P_hi, (void*)&GtT, (void*)&Y,
    (void*)&z,
  };
  hipLaunchCooperativeKernel((void*)mega_kernel, dim3(256), dim3(512),
                             kargs, 0, stream);
}

// Round 26
// 47.934 us; speedup vs baseline: 4.3495x; 4.3495x over previous
//
#include <hip/hip_runtime.h>
#include <hip/hip_bf16.h>

// NonLocalBlock fp32 -> reduced bf16 MFMA, MI355X.  FINAL (r22 config).
// Journey summary: 289.7us (fp32 VALU) -> 176 (split-bf16 MFMA) -> 91 (LDS
// pipeline) -> 57 (reduced math: drop p_lo/e_lo/g_lo/t_lo, exp2, trunc-pack,
// ones-MFMA denom) -> 47.6 (no-partials single-pass attn + linear GtT +
// asm 3-deep load pipeline). Measured decomposition (r24 8x-attn diagnostic):
// attn 17.9us, convs ~8-10us, ~20us graph-replay/dispatch overhead (harness
// floor; r25's cooperative mega-kernel made it 4x WORSE -- grid.sync ~80us).
// Error budget (validated r8-r17): check on z attenuates y-errors ~0.11x;
// absmax 7.63e-6 vs threshold 3.2e-5.
#define BATCH 2
#define CIN   64
#define COUT  32
#define HW    6400
#define PB    (COUT*HW)      // 204800 elems per batch (M-view 6400x32)
#define XB    (CIN*HW)
#define LOG2E 1.4426950408889634f

typedef __attribute__((ext_vector_type(8))) short  bf16x8;
typedef __attribute__((ext_vector_type(4))) float  f32x4;

typedef unsigned short ushort;
typedef unsigned int   uint;

__device__ inline uint pk2(float a, float b) {   // RNE pack (conv3 only)
  __hip_bfloat162 h = __float22bfloat162_rn(make_float2(a, b));
  union { __hip_bfloat162 h2; uint u; } cv; cv.h2 = h;
  return cv.u;
}
// truncation pack: lo short = bf16_trunc(a), hi short = bf16_trunc(b)
__device__ inline uint pkt(float a, float b) {
  return (__float_as_uint(b) & 0xFFFF0000u) | (__float_as_uint(a) >> 16);
}

#define MFMA16(a, bop, c) __builtin_amdgcn_mfma_f32_16x16x32_bf16((a), (bop), (c), 0, 0, 0)

// ---------------------------------------------------------------------------
// Kernel 1: three 1x1 convs -> bf16 buffers.
// theta (0): *LOG2E -> T_hi (flat [o][s]).  phi (1): -> P_hi (flat [o][s]).
// g (2): written DIRECTLY into the packed linear-fragment layout GtT:
//   value at (o,s) is G_M[m][c], m = o*200+(s>>5), c = s&31.
//   pk = inv_sigma(m&31); lane = (pk>>3)*16 + (c&15); h = c>>4
//   GtT flat idx = (m>>5)*1024 + h*512 + lane*8 + (pk&7)
// grid (50, 6, B) x 128.
// ---------------------------------------------------------------------------
__global__ __launch_bounds__(128) void conv3_kernel(
    const float* __restrict__ x,
    const float* __restrict__ w0, const float* __restrict__ bb0,   // theta
    const float* __restrict__ w1, const float* __restrict__ bb1,   // phi
    const float* __restrict__ w2, const float* __restrict__ bb2,   // g
    ushort* __restrict__ T_hi, ushort* __restrict__ P_hi,
    ushort* __restrict__ GtT) {
  const int which = blockIdx.y >> 1;
  const int oh    = blockIdx.y & 1;               // o-half: 16 channels
  const float* w  = (which == 0) ? w0 : (which == 1) ? w1 : w2;
  const float* bv = (which == 0) ? bb0 : (which == 1) ? bb1 : bb2;
  const int b = blockIdx.z;
  const int s = blockIdx.x * 128 + threadIdx.x;   // 50*128 == 6400

  __shared__ float wsm[16 * CIN];                 // 4 KiB (this half's rows)
  for (int i = threadIdx.x; i < 16 * CIN; i += 128)
    wsm[i] = w[oh * 16 * CIN + i];
  __syncthreads();

  float xr[CIN];
#pragma unroll
  for (int c = 0; c < CIN; ++c) xr[c] = x[b * XB + c * HW + s];   // coalesced

  for (int oi = 0; oi < 16; ++oi) {
    const int o = oh * 16 + oi;
    const float4* wr = (const float4*)&wsm[oi * CIN];
    float acc = 0.f;
#pragma unroll
    for (int q = 0; q < CIN / 4; ++q) {
      float4 wv = wr[q];
      acc += wv.x * xr[4*q] + wv.y * xr[4*q+1] + wv.z * xr[4*q+2] + wv.w * xr[4*q+3];
    }
    acc += bv[o];
    if (which == 0) acc *= LOG2E;                 // exp(S) == exp2(S*log2e)
    const ushort hb = (ushort)(pk2(acc, 0.f) & 0xFFFFu);
    if (which == 2) {
      const int m  = o * 200 + (s >> 5);          // M-view row (= key) of value
      const int mm = m & 31;
      const int pk = 16*((mm>>3)&1) + 8*((mm>>2)&1) + 4*((mm>>4)&1) + (mm&3);
      const int ln = (pk >> 3) * 16 + (s & 15);   // attn lane holding it
      const int idx = ((m >> 5) << 10) + (((s >> 4) & 1) << 9)
                    + (ln << 3) + (pk & 7);
      GtT[b * PB + idx] = hb;                     // scattered 2B, L2-merged
    } else {
      const int f = b * PB + o * HW + s;
      if (which == 0) T_hi[f] = hb; else P_hi[f] = hb;
    }
  }
}

// ---------------------------------------------------------------------------
// Kernel 2: fused attention, FULL keys per block, 64 q/block, asm 3-deep
// load pipeline + packed linear GtT fragment loads.
// grid (100 q-tiles, B) x 512 (8 waves). Wave w owns key groups w + t*8,
// t = 0..24. Buffers A/B/C hold one tile's 4 fragments; tile t in buffer t%3.
// Step s: s_waitcnt vmcnt(8) -> sched_barrier(0) -> compute(buf s%3) ->
// asm-issue tile s+3. Tail: vmcnt(8/8/4/0).
// Math (validated): S' = p_hi*t_hi; e = exp2(S'); e' = bf16_trunc(e);
//       Y += e'*g_hi; D = MFMA(e', ones)  [consistent num & denom].
// ---------------------------------------------------------------------------
__global__ __launch_bounds__(512, 2) void attn_kernel(
    const ushort* __restrict__ T_hi, const ushort* __restrict__ P_hi,
    const ushort* __restrict__ GtT,
    float* __restrict__ Y) {   // [B][HW][32] final normalized y (M-view)
  const int b     = blockIdx.y;
  const int q_blk = blockIdx.x;          // 0..99, 64 queries each
  const int tid   = threadIdx.x;
  const int w     = tid >> 6;            // wave 0..7 = key slice
  const int lane  = tid & 63;
  const int l15   = lane & 15;
  const int g     = lane >> 4;

  __shared__ float yl[8 * 16 * 33 + 8 * 16];   // epilogue only (17.4 KB)

  const int kbase = w * 32;              // this wave's first key; stride 256

  // T fragments (theta*log2e) for q-subtiles s2 = 0..3
  bf16x8 t_hi[4];
#pragma unroll
  for (int s2 = 0; s2 < 4; ++s2) {
    const int qrow = q_blk * 64 + s2 * 16 + l15;
    t_hi[s2] = *(const bf16x8*)&T_hi[b * PB + qrow * 32 + g * 8];
  }
  // drain compiler-issued loads BEFORE the asm pipeline starts
  asm volatile("s_waitcnt vmcnt(0)" ::: "memory");
  __builtin_amdgcn_sched_barrier(0);

  // constant ones B-fragment: chan row 0 (lanes l15==0) = 1.0, rest 0
  union { uint u[4]; bf16x8 v; } g2u;
  {
    const uint ov = (l15 == 0) ? 0x3F803F80u : 0u;
    g2u.u[0] = ov; g2u.u[1] = ov; g2u.u[2] = ov; g2u.u[3] = ov;
  }
  const bf16x8 g2 = g2u.v;

  // per-lane fragment base sources
  const ushort* pg = P_hi + b * PB + (kbase + l15) * 32 + g * 8;
  const ushort* gg = GtT + b * PB + (w << 10) + lane * 8;

  f32x4 acc0[4] = {{0,0,0,0},{0,0,0,0},{0,0,0,0},{0,0,0,0}};  // chans 0..15
  f32x4 acc1[4] = {{0,0,0,0},{0,0,0,0},{0,0,0,0},{0,0,0,0}};  // chans 16..31
  f32x4 acc2[4] = {{0,0,0,0},{0,0,0,0},{0,0,0,0},{0,0,0,0}};  // denom (chan0)

  bf16x8 paA, pbA, g0A, g1A;
  bf16x8 paB, pbB, g0B, g1B;
  bf16x8 paC, pbC, g0C, g1C;

#define ISSUE(SUF, t) do {                                                   \
    const ushort* _pp = pg + (size_t)(t) * 8192;                             \
    const ushort* _gp = gg + (size_t)(t) * 8192;                             \
    asm volatile("global_load_dwordx4 %0, %1, off"                           \
                 : "=&v"(pa##SUF) : "v"(_pp));                               \
    asm volatile("global_load_dwordx4 %0, %1, off"                           \
                 : "=&v"(pb##SUF) : "v"(_pp + 512));                         \
    asm volatile("global_load_dwordx4 %0, %1, off"                           \
                 : "=&v"(g0##SUF) : "v"(_gp));                               \
    asm volatile("global_load_dwordx4 %0, %1, off"                           \
                 : "=&v"(g1##SUF) : "v"(_gp + 512));                         \
  } while (0)

#define WAITVM(n) do {                                                       \
    asm volatile("s_waitcnt vmcnt(" #n ")" ::: "memory");                    \
    __builtin_amdgcn_sched_barrier(0);                                       \
  } while (0)

#define COMPUTE(SUF)                                                         \
  _Pragma("unroll")                                                          \
  for (int s2 = 0; s2 < 4; ++s2) {                                           \
    f32x4 sa = {0.f, 0.f, 0.f, 0.f};                                         \
    f32x4 sb = {0.f, 0.f, 0.f, 0.f};                                         \
    sa = MFMA16(pa##SUF, t_hi[s2], sa);                                      \
    sb = MFMA16(pb##SUF, t_hi[s2], sb);                                      \
    const float ea0 = __builtin_amdgcn_exp2f(sa[0]);                         \
    const float ea1 = __builtin_amdgcn_exp2f(sa[1]);                         \
    const float ea2 = __builtin_amdgcn_exp2f(sa[2]);                         \
    const float ea3 = __builtin_amdgcn_exp2f(sa[3]);                         \
    const float eb0 = __builtin_amdgcn_exp2f(sb[0]);                         \
    const float eb1 = __builtin_amdgcn_exp2f(sb[1]);                         \
    const float eb2 = __builtin_amdgcn_exp2f(sb[2]);                         \
    const float eb3 = __builtin_amdgcn_exp2f(sb[3]);                         \
    union { uint u[4]; bf16x8 v; } ph;                                       \
    ph.u[0] = pkt(ea0, ea1); ph.u[1] = pkt(ea2, ea3);                        \
    ph.u[2] = pkt(eb0, eb1); ph.u[3] = pkt(eb2, eb3);                        \
    acc0[s2] = MFMA16(ph.v, g0##SUF, acc0[s2]);                              \
    acc1[s2] = MFMA16(ph.v, g1##SUF, acc1[s2]);                              \
    acc2[s2] = MFMA16(ph.v, g2, acc2[s2]);                                   \
  }

  // prologue: tiles 0,1,2 in flight (12 loads)
  ISSUE(A, 0);
  ISSUE(B, 1);
  ISSUE(C, 2);

  // steps 0..20 (7 triples): always 2 tiles in flight behind the wait
  for (int i = 0; i < 21; i += 3) {
    WAITVM(8); COMPUTE(A); ISSUE(A, i + 3);
    WAITVM(8); COMPUTE(B); ISSUE(B, i + 4);
    WAITVM(8); COMPUTE(C); ISSUE(C, i + 5);
  }
  // tail: steps 21..24 (tiles 21..24; issues stop at tile 24)
  WAITVM(8); COMPUTE(A); ISSUE(A, 24);   // step 21, issue last tile
  WAITVM(8); COMPUTE(B);                 // step 22
  WAITVM(4); COMPUTE(C);                 // step 23
  WAITVM(0); COMPUTE(A);                 // step 24

#undef ISSUE
#undef WAITVM
#undef COMPUTE

  // epilogue: combine the 8 key-slice waves via LDS, 4 passes of 16 queries;
  // divide and write FINAL y (M-view flat).
  float* dl = yl + 8 * 16 * 33;
  const int c   = tid & 31;
  const int row = (tid >> 5) & 15;       // 512 threads = 16 rows x 32 chans

#pragma unroll
  for (int p = 0; p < 4; ++p) {
    __syncthreads();                     // all waves ready / yl reusable
    {
      const int s2 = p;
#pragma unroll
      for (int r = 0; r < 4; ++r) {
        yl[(w * 16 + 4 * g + r) * 33 + l15]      = acc0[s2][r];
        yl[(w * 16 + 4 * g + r) * 33 + 16 + l15] = acc1[s2][r];
      }
      if (l15 == 0) {                    // chan-0 lanes hold the denominator
#pragma unroll
        for (int r = 0; r < 4; ++r)
          dl[w * 16 + 4 * g + r] = acc2[s2][r];
      }
    }
    __syncthreads();

    float y = 0.f, d = 0.f;
#pragma unroll
    for (int k2 = 0; k2 < 8; ++k2) {
      y += yl[(k2 * 16 + row) * 33 + c];
      d += dl[k2 * 16 + row];
    }
    const int qrow = q_blk * 64 + p * 16 + row;
    Y[(size_t)b * PB + qrow * 32 + c] = y / d;
  }
}

// ---------------------------------------------------------------------------
// Kernel 3: final 1x1 conv (reads final y flat as the [o][s] view).
// grid (50, 2, B) x 128.
// ---------------------------------------------------------------------------
__global__ __launch_bounds__(128) void conv_out_kernel(
    const float* __restrict__ Y, const float* __restrict__ wy,
    const float* __restrict__ by, float* __restrict__ z) {
  const int b  = blockIdx.z;
  const int ih = blockIdx.y;            // i-half: 32 channels
  const int s  = blockIdx.x * 128 + threadIdx.x;

  __shared__ float wsm[32 * COUT];      // 4 KiB (this half's rows)
  for (int i = threadIdx.x; i < 32 * COUT; i += 128)
    wsm[i] = wy[ih * 32 * COUT + i];
  __syncthreads();

  float yr[COUT];
#pragma unroll
  for (int o = 0; o < COUT; ++o)
    yr[o] = Y[(size_t)b * PB + o * HW + s];

  for (int ii = 0; ii < 32; ++ii) {
    const int i = ih * 32 + ii;
    const float4* wr = (const float4*)&wsm[ii * COUT];
    float acc = 0.f;
#pragma unroll
    for (int q = 0; q < COUT / 4; ++q) {
      float4 wv = wr[q];
      acc += wv.x * yr[4*q] + wv.y * yr[4*q+1] + wv.z * yr[4*q+2] + wv.w * yr[4*q+3];
    }
    z[(size_t)b * XB + i * HW + s] = acc + by[i];
  }
}

// ---------------------------------------------------------------------------
extern "C" void kernel_launch(void* const* d_in, const int* in_sizes, int n_in,
                              void* d_out, int out_size, void* d_ws, size_t ws_size,
                              hipStream_t stream) {
  const float* x       = (const float*)d_in[0];
  const float* w_g     = (const float*)d_in[1];
  const float* b_g     = (const float*)d_in[2];
  const float* w_phi   = (const float*)d_in[3];
  const float* b_phi   = (const float*)d_in[4];
  const float* w_theta = (const float*)d_in[5];
  const float* b_theta = (const float*)d_in[6];
  const float* w_y     = (const float*)d_in[7];
  const float* b_y     = (const float*)d_in[8];
  float* z = (float*)d_out;

  char* base = (char*)d_ws;
  const size_t BF = (size_t)BATCH * PB * sizeof(ushort);  // 819200 B
  ushort* T_hi = (ushort*)(base);
  ushort* P_hi = (ushort*)(base + 1 * BF);
  ushort* GtT  = (ushort*)(base + 2 * BF);
  float*  Y    = (float*)(base + 3 * BF);                  // B*PB f32 final y

  conv3_kernel<<<dim3(50, 6, BATCH), 128, 0, stream>>>(
      x, w_theta, b_theta, w_phi, b_phi, w_g, b_g,
      T_hi, P_hi, GtT);
  attn_kernel<<<dim3(100, BATCH), 512, 0, stream>>>(
      T_hi, P_hi, GtT, Y);
  conv_out_kernel<<<dim3(50, 2, BATCH), 128, 0, stream>>>(Y, w_y, b_y, z);
}